// Round 13
// baseline (184.175 us; speedup 1.0000x reference)
//
#include <hip/hip_runtime.h>
#include <cfloat>
#include <climits>

// Retriever: cosine-sim top-5 over 100k knowledge vectors + gather.
// v13: sims stages ke f32 via global_load_lds into a DOUBLE-BUFFERED LDS
// tile (in-flight bytes pinned in LDS, not VGPR), counted s_waitcnt
// vmcnt(12) so the next tile's 12-load burst streams across K-loop +
// barriers + scan (T3/T4). K-loop converts f32->bf16 in-reg (4 v_perm/step),
// Gram-MFMA norms, quarter-parallel top-8 tail. 256 persistent blocks
// (1/CU, 102KB LDS). Then merge -> top-16 -> exact f32 rescore -> gather.

#define BQ 64
#define DD 768
#define NK 100000
#define LK 32
#define K_TOP 5
#define TROWS 16                    // ke rows per tile
#define NTIL (NK / TROWS)           // 6250 (exact)
#define NBLKS 256                   // persistent sims blocks (1/CU)
#define T_CAND 16                   // rescore candidate count

typedef __attribute__((ext_vector_type(8))) short short8;
typedef __attribute__((ext_vector_type(4))) float f32x4;

static __device__ __forceinline__ ushort bf16_rtn(float x) {
    uint u = __float_as_uint(x);
    return (ushort)((u + 0x7FFFu + ((u >> 16) & 1u)) >> 16);
}

static __device__ __forceinline__ void gload_lds16(const float* gsrc, float* ldsdst) {
    __builtin_amdgcn_global_load_lds(
        (const __attribute__((address_space(1))) unsigned int*)gsrc,
        (__attribute__((address_space(3))) unsigned int*)ldsdst,
        16, 0, 0);
}

#define INS8(v, n, va, ia)                                                  \
    _Pragma("unroll")                                                       \
    for (int m_ = 0; m_ < 8; ++m_) {                                        \
        if ((v) > va[m_]) {                                                 \
            float tv_ = va[m_]; va[m_] = (v); (v) = tv_;                    \
            int ti_ = ia[m_]; ia[m_] = (n); (n) = ti_;                      \
        }                                                                   \
    }

// ---------- phase 0: query -> normalized bf16 in FRAGMENT-MAJOR layout ----------
// qf[((kt*4 + (b>>4))*64 + lg*16 + (b&15))*8 + j] = bf16(q[b][kt*32+lg*8+j] * rq)
__global__ __launch_bounds__(256) void prep_kernel(const float* __restrict__ q,
                                                   ushort* __restrict__ qf,
                                                   float* __restrict__ qn) {
    const int b = blockIdx.x, t = threadIdx.x;
    __shared__ float red[4];
    float v[3];
    float s = 0.f;
#pragma unroll
    for (int i = 0; i < 3; ++i) {
        v[i] = q[b * DD + t + i * 256];
        s = fmaf(v[i], v[i], s);
    }
    for (int off = 32; off > 0; off >>= 1) s += __shfl_down(s, off, 64);
    if ((t & 63) == 0) red[t >> 6] = s;
    __syncthreads();
    const float tot = red[0] + red[1] + red[2] + red[3];
    const float rq = rsqrtf(tot);
    const int qb = b >> 4, bi = b & 15;
#pragma unroll
    for (int i = 0; i < 3; ++i) {
        const int k = t + i * 256;
        const int kt = k >> 5, lg = (k >> 3) & 3, j = k & 7;
        qf[((size_t)(kt * 4 + qb) * 64 + lg * 16 + bi) * 8 + j] = bf16_rtn(v[i] * rq);
    }
    if (t == 0) qn[b] = sqrtf(tot);
}

// ---------- phase 1: persistent sims, LDS-dbuf gload staging, counted vmcnt ----------
// Swizzle (rule 21 both-sides): LDS[row*3072 + z] = ke_bytes[row][z ^ swb],
// swb = (row&7)<<4, applied on the per-lane GLOBAL source (dest is linear);
// reads XOR the same bits -> ds_read_b128 conflict-reduced.
__global__ __launch_bounds__(256) void sims_kernel(const ushort* __restrict__ qf,
                                                   const float* __restrict__ ke,
                                                   float2* __restrict__ pv) {
    __shared__ float Bf[2][TROWS * DD];    // 2 x 49152 B raw f32, src-swizzled
    __shared__ float S[BQ][17];            // sims tile (bank-spread)

    const int t = threadIdx.x;
    const int w = t >> 6, l = t & 63;
    const int lg = l >> 4, li = l & 15;
    const int qd = t & 63, jq = t >> 6;    // tail: query + column-quarter

    float v8[8]; int i8[8];
#pragma unroll
    for (int m = 0; m < 8; ++m) { v8[m] = -FLT_MAX; i8[m] = INT_MAX; }

// issue one tile's stage: 12 gload_lds per wave (4 rows x 3KB), source-swizzled
#define ISSUE(tl, buf) do {                                                 \
        _Pragma("unroll")                                                   \
        for (int i_ = 0; i_ < 4; ++i_) {                                    \
            const int r_ = w * 4 + i_;                                      \
            const float* gr_ = ke + (size_t)((tl) * TROWS + r_) * DD;       \
            const int swb_ = (r_ & 7) << 4;                                 \
            const int lf_ = ((l * 16) ^ swb_) >> 2;                         \
            float* ld_ = &Bf[buf][r_ * DD];                                 \
            _Pragma("unroll")                                               \
            for (int c_ = 0; c_ < 3; ++c_)                                  \
                gload_lds16(gr_ + c_ * 256 + lf_, ld_ + c_ * 256);          \
        }                                                                   \
    } while (0)

    int tile = blockIdx.x;
    int cur = 0;

    // prologue: tile-0 stage first (oldest in vmcnt queue), then A preload
    ISSUE(tile, 0);
    const ushort* aq = qf + (size_t)w * 512 + l * 8;
    short8 A[24];
#pragma unroll
    for (int p = 0; p < 24; ++p) A[p] = *(const short8*)(aq + p * 2048);

    while (true) {
        const int nxt = tile + NBLKS;

        __builtin_amdgcn_sched_barrier(0);
        if (nxt < NTIL) {
            ISSUE(nxt, cur ^ 1);               // streams across K-loop+scan
            __builtin_amdgcn_sched_barrier(0);
            asm volatile("s_waitcnt vmcnt(12)" ::: "memory");  // drain tile t only
        } else {
            asm volatile("s_waitcnt vmcnt(0)" ::: "memory");
        }
        __builtin_amdgcn_sched_barrier(0);
        __builtin_amdgcn_s_barrier();          // all waves' tile-t rows landed
        __builtin_amdgcn_sched_barrier(0);

        // ---- K-loop: LDS f32 (swizzled) -> v_perm bf16 -> 2 MFMA ----
        const char* bb = (const char*)&Bf[cur][0];
        const int rowb = li * 3072;
        const int sw = (li & 7) << 4;
        f32x4 acc = (f32x4){0.f, 0.f, 0.f, 0.f};
        f32x4 ncc = (f32x4){0.f, 0.f, 0.f, 0.f};
        f32x4 b0[2], b1[2];                    // ring-2
        {
            const int y = lg * 32;
            b0[0] = *(const f32x4*)(bb + rowb + (y ^ sw));
            b1[0] = *(const f32x4*)(bb + rowb + ((y + 16) ^ sw));
        }
#pragma unroll
        for (int kt = 0; kt < 24; ++kt) {
            const int cb = kt & 1;
            if (kt < 23) {
                const int y = (kt + 1) * 128 + lg * 32;
                b0[cb ^ 1] = *(const f32x4*)(bb + rowb + (y ^ sw));
                b1[cb ^ 1] = *(const f32x4*)(bb + rowb + ((y + 16) ^ sw));
            }
            union { short8 s8; uint u[4]; } pk;
            pk.u[0] = __builtin_amdgcn_perm(__float_as_uint(b0[cb][1]),
                                            __float_as_uint(b0[cb][0]), 0x07060302u);
            pk.u[1] = __builtin_amdgcn_perm(__float_as_uint(b0[cb][3]),
                                            __float_as_uint(b0[cb][2]), 0x07060302u);
            pk.u[2] = __builtin_amdgcn_perm(__float_as_uint(b1[cb][1]),
                                            __float_as_uint(b1[cb][0]), 0x07060302u);
            pk.u[3] = __builtin_amdgcn_perm(__float_as_uint(b1[cb][3]),
                                            __float_as_uint(b1[cb][2]), 0x07060302u);
            acc = __builtin_amdgcn_mfma_f32_16x16x32_bf16(A[kt], pk.s8, acc, 0, 0, 0);
            ncc = __builtin_amdgcn_mfma_f32_16x16x32_bf16(pk.s8, pk.s8, ncc, 0, 0, 0);
        }

        // ---- row norm from Gram diag: C[i][i] at lane ((i>>2)<<4)|i, reg i&3 ----
        float x = ncc[li & 3];
        float dsq = __shfl(x, ((li >> 2) << 4) | li, 64);
        float rk = rsqrtf(dsq);

        // ---- S-tile (C layout: col(n)=li, row(q16)=lg*4+r), scaled ----
#pragma unroll
        for (int r = 0; r < 4; ++r) S[w * 16 + lg * 4 + r][li] = acc[r] * rk;
        asm volatile("s_waitcnt lgkmcnt(0)" ::: "memory");
        __builtin_amdgcn_sched_barrier(0);
        __builtin_amdgcn_s_barrier();
        __builtin_amdgcn_sched_barrier(0);

        // ---- per-tile top-8, all 256 threads (query qd, column quarter jq) ----
        {
            const int nb = tile * TROWS + jq * 4;
#pragma unroll
            for (int j = 0; j < 4; ++j) {
                float v = S[qd][jq * 4 + j]; int n = nb + j;
                INS8(v, n, v8, i8);
            }
        }
        if (nxt >= NTIL) break;
        tile = nxt; cur ^= 1;
    }
#undef ISSUE

    // ---- final 4-way quarter merge (reuse Bf[0] as staging: 16KB) ----
    __syncthreads();
    float2* mg = (float2*)(&Bf[0][0]);
#pragma unroll
    for (int m = 0; m < 8; ++m) mg[t * 8 + m] = make_float2(v8[m], __int_as_float(i8[m]));
    __syncthreads();
    if (t < BQ) {
        float vf[8]; int nf[8];
#pragma unroll
        for (int m = 0; m < 8; ++m) { vf[m] = -FLT_MAX; nf[m] = INT_MAX; }
        for (int s = 0; s < 4; ++s) {
            const float2* rowp = &mg[(t + s * 64) * 8];
#pragma unroll
            for (int m = 0; m < 8; ++m) {
                float v = rowp[m].x; int n = __float_as_int(rowp[m].y);
                INS8(v, n, vf, nf);
            }
        }
        float2* dst = pv + ((size_t)t * NBLKS + blockIdx.x) * 8;
#pragma unroll
        for (int m = 0; m < 8; ++m) dst[m] = make_float2(vf[m], __int_as_float(nf[m]));
    }
}

// ---------- phase 2: merge 256x8 -> top-16 -> exact f32 rescore -> top-5 -> gather ----------
__global__ __launch_bounds__(256) void merge_rescore_kernel(
    const float2* __restrict__ pv,
    const float* __restrict__ q, const float* __restrict__ ke,
    const int* __restrict__ kf, const float* __restrict__ qn,
    float* __restrict__ out) {
    const int qi = blockIdx.x, t = threadIdx.x;
    __shared__ float sv[256][8];
    __shared__ int   si[256][8];
    __shared__ int   ci[T_CAND];
    __shared__ float cs_[T_CAND];
    __shared__ int   fi[K_TOP];

    float v8[8]; int i8[8];
#pragma unroll
    for (int m = 0; m < 8; ++m) { v8[m] = -FLT_MAX; i8[m] = INT_MAX; }

    // coalesced scan of this query's partials [NBLKS*8 = 2048]
    const float2* src = pv + (size_t)qi * NBLKS * 8;
#pragma unroll 4
    for (int c = t; c < NBLKS * 8; c += 256) {
        float2 e = src[c];
        float v = e.x; int n = __float_as_int(e.y);
        INS8(v, n, v8, i8);
    }
#pragma unroll
    for (int m = 0; m < 8; ++m) { sv[t][m] = v8[m]; si[t][m] = i8[m]; }
    __syncthreads();

    // tree merge 256 -> 64 -> 16 -> 4 rows (top-8 each; global rank<=8 survives)
    for (int active = 64; active >= 4; active >>= 2) {
        if (t < active) {
#pragma unroll
            for (int m = 0; m < 8; ++m) { v8[m] = -FLT_MAX; i8[m] = INT_MAX; }
            for (int s = 0; s < 4; ++s) {
                int row = t * 4 + s;
#pragma unroll
                for (int m = 0; m < 8; ++m) {
                    float v = sv[row][m]; int n = si[row][m];
                    INS8(v, n, v8, i8);
                }
            }
        }
        __syncthreads();
        if (t < active) {
#pragma unroll
            for (int m = 0; m < 8; ++m) { sv[t][m] = v8[m]; si[t][m] = i8[m]; }
        }
        __syncthreads();
    }

    // thread 0: 4 rows x 8 -> top-16
    if (t == 0) {
        float v16[T_CAND]; int i16[T_CAND];
#pragma unroll
        for (int m = 0; m < T_CAND; ++m) { v16[m] = -FLT_MAX; i16[m] = INT_MAX; }
        for (int row = 0; row < 4; ++row) {
#pragma unroll
            for (int m = 0; m < 8; ++m) {
                float v = sv[row][m]; int n = si[row][m];
#pragma unroll
                for (int p = 0; p < T_CAND; ++p) {
                    if (v > v16[p]) {
                        float tv = v16[p]; v16[p] = v; v = tv;
                        int ti = i16[p]; i16[p] = n; n = ti;
                    }
                }
            }
        }
#pragma unroll
        for (int m = 0; m < T_CAND; ++m) ci[m] = i16[m];
    }
    __syncthreads();

    // exact f32 rescore; wave w -> candidates w*4..w*4+3
    {
        const int w = t >> 6, lane = t & 63;
        for (int cc = 0; cc < 4; ++cc) {
            int c = w * 4 + cc;
            int row = ci[c];
            const float* kp = ke + (size_t)row * DD + lane * 12;
            const float* qp = q + qi * DD + lane * 12;
            float d = 0.f, ks = 0.f;
#pragma unroll
            for (int i = 0; i < 12; ++i) {
                float kv = kp[i];
                d = fmaf(qp[i], kv, d);
                ks = fmaf(kv, kv, ks);
            }
#pragma unroll
            for (int off = 32; off > 0; off >>= 1) {
                d += __shfl_xor(d, off, 64);
                ks += __shfl_xor(ks, off, 64);
            }
            if (lane == 0)
                cs_[c] = d / fmaxf(qn[qi] * sqrtf(ks), 1e-8f);
        }
    }
    __syncthreads();

    // final top-5 of 16 (tie -> lower index)
    if (t == 0) {
        float v5[K_TOP]; int i5[K_TOP];
#pragma unroll
        for (int m = 0; m < K_TOP; ++m) { v5[m] = -FLT_MAX; i5[m] = INT_MAX; }
        for (int c = 0; c < T_CAND; ++c) {
            float v = cs_[c]; int n = ci[c];
#pragma unroll
            for (int m = 0; m < K_TOP; ++m) {
                bool take = (v > v5[m]) || (v == v5[m] && n < i5[m]);
                if (take) {
                    float tv = v5[m]; v5[m] = v; v = tv;
                    int ti = i5[m]; i5[m] = n; n = ti;
                }
            }
        }
#pragma unroll
        for (int m = 0; m < K_TOP; ++m) fi[m] = i5[m];
    }
    __syncthreads();

    // gather knowledge_full rows (ints < 30000 exact in f32)
    for (int pos = t; pos < K_TOP * LK; pos += 256) {
        int m = pos >> 5, lgi = pos & 31;
        out[(qi * K_TOP + m) * LK + lgi] = (float)kf[(size_t)fi[m] * LK + lgi];
    }
    // gather embed rows
    const int EO = BQ * K_TOP * LK;  // 10240
    for (int m = 0; m < K_TOP; ++m) {
        const float4* srcp = (const float4*)(ke + (size_t)fi[m] * DD);
        float4* dstp = (float4*)(out + EO + (size_t)(qi * K_TOP + m) * DD);
        for (int pos = t; pos < DD / 4; pos += 256) dstp[pos] = srcp[pos];
    }
}

extern "C" void kernel_launch(void* const* d_in, const int* in_sizes, int n_in,
                              void* d_out, int out_size, void* d_ws, size_t ws_size,
                              hipStream_t stream) {
    const float* query = (const float*)d_in[0];
    const float* ke    = (const float*)d_in[1];
    const int*   kf    = (const int*)d_in[2];
    float* out = (float*)d_out;

    // ws layout: pv [64][256][8] float2 (1.05 MB) | qf [24*4*64*8] ushort | qn[64]
    float2* pv = (float2*)d_ws;
    ushort* qf = (ushort*)((char*)d_ws + (size_t)BQ * NBLKS * 8 * sizeof(float2));
    float*  qn = (float*)((char*)qf + (size_t)24 * 4 * 64 * 8 * sizeof(ushort));

    prep_kernel<<<BQ, 256, 0, stream>>>(query, qf, qn);
    sims_kernel<<<NBLKS, 256, 0, stream>>>(qf, ke, pv);
    merge_rescore_kernel<<<BQ, 256, 0, stream>>>(pv, query, ke, kf, qn, out);
}

// Round 14
// 172.967 us; speedup vs baseline: 1.0648x; 1.0648x over previous
//
#include <hip/hip_runtime.h>
#include <cfloat>
#include <climits>

// Retriever: cosine-sim top-5 over 100k knowledge vectors + gather.
// v14 = v12 (best, 145.5us) + depth-2 register ping-pong staging:
// loads for tile T+2 issue into the buffer freed by tile T's convert, so
// each 12-load burst gets TWO periods to land (covers ~900-1500cy latency;
// v12 gave it <1 period -> ~500cy stall per wave per tile). Buffers are
// statically indexed (unrolled pair loop + static tail) per rule #20.
// K-loop stays VMEM-free (A preloaded once). Gram-MFMA norms, swizzled LDS,
// quarter-parallel top-8. Then merge -> top-16 -> exact f32 rescore -> gather.

#define BQ 64
#define DD 768
#define NK 100000
#define LK 32
#define K_TOP 5
#define TROWS 16                    // ke rows per tile
#define NTIL (NK / TROWS)           // 6250 (exact)
#define NBLKS 512                   // persistent sims blocks (2/CU)
#define T_CAND 16                   // rescore candidate count

typedef __attribute__((ext_vector_type(8))) short short8;
typedef __attribute__((ext_vector_type(4))) float f32x4;

static __device__ __forceinline__ ushort bf16_rtn(float x) {
    uint u = __float_as_uint(x);
    return (ushort)((u + 0x7FFFu + ((u >> 16) & 1u)) >> 16);
}

#define INS8(v, n, va, ia)                                                  \
    _Pragma("unroll")                                                       \
    for (int m_ = 0; m_ < 8; ++m_) {                                        \
        if ((v) > va[m_]) {                                                 \
            float tv_ = va[m_]; va[m_] = (v); (v) = tv_;                    \
            int ti_ = ia[m_]; ia[m_] = (n); (n) = ti_;                      \
        }                                                                   \
    }

// ---------- phase 0: query -> normalized bf16 in FRAGMENT-MAJOR layout ----------
// qf[((kt*4 + (b>>4))*64 + lg*16 + (b&15))*8 + j] = bf16(q[b][kt*32+lg*8+j] * rq)
__global__ __launch_bounds__(256) void prep_kernel(const float* __restrict__ q,
                                                   ushort* __restrict__ qf,
                                                   float* __restrict__ qn) {
    const int b = blockIdx.x, t = threadIdx.x;
    __shared__ float red[4];
    float v[3];
    float s = 0.f;
#pragma unroll
    for (int i = 0; i < 3; ++i) {
        v[i] = q[b * DD + t + i * 256];
        s = fmaf(v[i], v[i], s);
    }
    for (int off = 32; off > 0; off >>= 1) s += __shfl_down(s, off, 64);
    if ((t & 63) == 0) red[t >> 6] = s;
    __syncthreads();
    const float tot = red[0] + red[1] + red[2] + red[3];
    const float rq = rsqrtf(tot);
    const int qb = b >> 4, bi = b & 15;
#pragma unroll
    for (int i = 0; i < 3; ++i) {
        const int k = t + i * 256;
        const int kt = k >> 5, lg = (k >> 3) & 3, j = k & 7;
        qf[((size_t)(kt * 4 + qb) * 64 + lg * 16 + bi) * 8 + j] = bf16_rtn(v[i] * rq);
    }
    if (t == 0) qn[b] = sqrtf(tot);
}

// ---------- phase 1: persistent sims, depth-2 ping-pong staging ----------
__global__ __launch_bounds__(256, 2) void sims_kernel(const ushort* __restrict__ qf,
                                                      const float* __restrict__ ke,
                                                      float2* __restrict__ pv) {
    __shared__ ushort Bb[TROWS * DD];      // 24576 B single buffer, swizzled
    __shared__ float  S[BQ][17];           // sims tile (bank-spread)

    const int t = threadIdx.x;
    const int w = t >> 6, l = t & 63;
    const int lg = l >> 4, li = l & 15;
    const int qd = t & 63, jq = t >> 6;    // tail: query + column-quarter

    float v8[8]; int i8[8];
#pragma unroll
    for (int m = 0; m < 8; ++m) { v8[m] = -FLT_MAX; i8[m] = INT_MAX; }

    f32x4 srA[4][3], srB[4][3];            // two reg staging buffers
    const int b = blockIdx.x;

#define ISSUE(SR, tl) do {                                                  \
        const float* g_ = ke + (size_t)((tl) * TROWS + w * 4) * DD + l * 4; \
        _Pragma("unroll")                                                   \
        for (int i_ = 0; i_ < 4; ++i_)                                      \
            _Pragma("unroll")                                               \
            for (int c_ = 0; c_ < 3; ++c_)                                  \
                SR[i_][c_] = *(const f32x4*)(g_ + i_ * DD + c_ * 256);      \
    } while (0)

// full per-tile phase: convert SR -> Bb, re-issue SR for tile nn, barrier,
// VMEM-free K-loop, Gram norm, S, barrier, quarter-scan.
#define PROCESS(SR, tl, nn) do {                                            \
        char* bb_ = (char*)Bb;                                              \
        _Pragma("unroll")                                                   \
        for (int i_ = 0; i_ < 4; ++i_) {                                    \
            const int row_ = w * 4 + i_;                                    \
            const int base_ = row_ * 1536 + l * 8;                          \
            const int sw_ = (row_ & 7) << 4;                                \
            _Pragma("unroll")                                               \
            for (int c_ = 0; c_ < 3; ++c_) {                                \
                uint2 u_;                                                   \
                u_.x = __builtin_amdgcn_perm(__float_as_uint(SR[i_][c_][1]),\
                                             __float_as_uint(SR[i_][c_][0]),\
                                             0x07060302u);                  \
                u_.y = __builtin_amdgcn_perm(__float_as_uint(SR[i_][c_][3]),\
                                             __float_as_uint(SR[i_][c_][2]),\
                                             0x07060302u);                  \
                *(uint2*)(bb_ + ((base_ + c_ * 512) ^ sw_)) = u_;           \
            }                                                               \
        }                                                                   \
        if ((nn) < NTIL) ISSUE(SR, nn);                                     \
        asm volatile("s_waitcnt lgkmcnt(0)" ::: "memory");                  \
        __builtin_amdgcn_sched_barrier(0);                                  \
        __builtin_amdgcn_s_barrier();                                       \
        __builtin_amdgcn_sched_barrier(0);                                  \
        const int boff_ = li * 1536 + lg * 16;                              \
        const int bsw_ = (li & 7) << 4;                                     \
        f32x4 acc_ = (f32x4){0.f, 0.f, 0.f, 0.f};                           \
        f32x4 ncc_ = (f32x4){0.f, 0.f, 0.f, 0.f};                           \
        short8 br_[2];                                                      \
        br_[0] = *(const short8*)(bb_ + (boff_ ^ bsw_));                    \
        _Pragma("unroll")                                                   \
        for (int kt_ = 0; kt_ < 24; ++kt_) {                                \
            const int cb_ = kt_ & 1;                                        \
            if (kt_ < 23)                                                   \
                br_[cb_ ^ 1] = *(const short8*)(bb_ +                       \
                                    ((boff_ + (kt_ + 1) * 64) ^ bsw_));     \
            acc_ = __builtin_amdgcn_mfma_f32_16x16x32_bf16(                 \
                A[kt_], br_[cb_], acc_, 0, 0, 0);                           \
            ncc_ = __builtin_amdgcn_mfma_f32_16x16x32_bf16(                 \
                br_[cb_], br_[cb_], ncc_, 0, 0, 0);                         \
        }                                                                   \
        float x_ = ncc_[li & 3];                                            \
        float dsq_ = __shfl(x_, ((li >> 2) << 4) | li, 64);                 \
        float rk_ = rsqrtf(dsq_);                                           \
        _Pragma("unroll")                                                   \
        for (int r_ = 0; r_ < 4; ++r_)                                      \
            S[w * 16 + lg * 4 + r_][li] = acc_[r_] * rk_;                   \
        asm volatile("s_waitcnt lgkmcnt(0)" ::: "memory");                  \
        __builtin_amdgcn_sched_barrier(0);                                  \
        __builtin_amdgcn_s_barrier();                                       \
        __builtin_amdgcn_sched_barrier(0);                                  \
        {                                                                   \
            const int nb_ = (tl) * TROWS + jq * 4;                          \
            _Pragma("unroll")                                               \
            for (int j_ = 0; j_ < 4; ++j_) {                                \
                float v_ = S[qd][jq * 4 + j_]; int n_ = nb_ + j_;           \
                INS8(v_, n_, v8, i8);                                       \
            }                                                               \
        }                                                                   \
    } while (0)

    // prologue: two bursts in flight before anything waits
    ISSUE(srA, b);
    ISSUE(srB, b + NBLKS);                 // b+512 < 6250 always
    const ushort* aq = qf + (size_t)w * 512 + l * 8;
    short8 A[24];
#pragma unroll
    for (int p = 0; p < 24; ++p) A[p] = *(const short8*)(aq + p * 2048);

    // 6 pair-iterations: tiles b+k*512 (srA even k, srB odd k), k=0..11
    for (int k = 0; k < 12; k += 2) {
        PROCESS(srA, b + k * NBLKS, b + (k + 2) * NBLKS);
        PROCESS(srB, b + (k + 1) * NBLKS, b + (k + 3) * NBLKS);
    }
    // static tail: blocks b<106 own a 13th tile (issued at pair k=10, srA)
    if (b + 12 * NBLKS < NTIL) {
        PROCESS(srA, b + 12 * NBLKS, NTIL);
    }
#undef PROCESS
#undef ISSUE

    // ---- final 4-way quarter merge (reuse Bb as staging: 16KB <= 24KB) ----
    __syncthreads();
    float2* mg = (float2*)(&Bb[0]);
#pragma unroll
    for (int m = 0; m < 8; ++m) mg[t * 8 + m] = make_float2(v8[m], __int_as_float(i8[m]));
    __syncthreads();
    if (t < BQ) {
        float vf[8]; int nf[8];
#pragma unroll
        for (int m = 0; m < 8; ++m) { vf[m] = -FLT_MAX; nf[m] = INT_MAX; }
        for (int s = 0; s < 4; ++s) {
            const float2* rowp = &mg[(t + s * 64) * 8];
#pragma unroll
            for (int m = 0; m < 8; ++m) {
                float v = rowp[m].x; int n = __float_as_int(rowp[m].y);
                INS8(v, n, vf, nf);
            }
        }
        float2* dst = pv + ((size_t)t * NBLKS + blockIdx.x) * 8;
#pragma unroll
        for (int m = 0; m < 8; ++m) dst[m] = make_float2(vf[m], __int_as_float(nf[m]));
    }
}

// ---------- phase 2: merge 512x8 -> top-16 -> exact f32 rescore -> top-5 -> gather ----------
__global__ __launch_bounds__(256) void merge_rescore_kernel(
    const float2* __restrict__ pv,
    const float* __restrict__ q, const float* __restrict__ ke,
    const int* __restrict__ kf, const float* __restrict__ qn,
    float* __restrict__ out) {
    const int qi = blockIdx.x, t = threadIdx.x;
    __shared__ float sv[256][8];
    __shared__ int   si[256][8];
    __shared__ int   ci[T_CAND];
    __shared__ float cs_[T_CAND];
    __shared__ int   fi[K_TOP];

    float v8[8]; int i8[8];
#pragma unroll
    for (int m = 0; m < 8; ++m) { v8[m] = -FLT_MAX; i8[m] = INT_MAX; }

    // coalesced scan of this query's partials [NBLKS*8 = 4096]
    const float2* src = pv + (size_t)qi * NBLKS * 8;
#pragma unroll 4
    for (int c = t; c < NBLKS * 8; c += 256) {
        float2 e = src[c];
        float v = e.x; int n = __float_as_int(e.y);
        INS8(v, n, v8, i8);
    }
#pragma unroll
    for (int m = 0; m < 8; ++m) { sv[t][m] = v8[m]; si[t][m] = i8[m]; }
    __syncthreads();

    // tree merge 256 -> 64 -> 16 -> 4 rows (top-8 each; global rank<=8 survives)
    for (int active = 64; active >= 4; active >>= 2) {
        if (t < active) {
#pragma unroll
            for (int m = 0; m < 8; ++m) { v8[m] = -FLT_MAX; i8[m] = INT_MAX; }
            for (int s = 0; s < 4; ++s) {
                int row = t * 4 + s;
#pragma unroll
                for (int m = 0; m < 8; ++m) {
                    float v = sv[row][m]; int n = si[row][m];
                    INS8(v, n, v8, i8);
                }
            }
        }
        __syncthreads();
        if (t < active) {
#pragma unroll
            for (int m = 0; m < 8; ++m) { sv[t][m] = v8[m]; si[t][m] = i8[m]; }
        }
        __syncthreads();
    }

    // thread 0: 4 rows x 8 -> top-16
    if (t == 0) {
        float v16[T_CAND]; int i16[T_CAND];
#pragma unroll
        for (int m = 0; m < T_CAND; ++m) { v16[m] = -FLT_MAX; i16[m] = INT_MAX; }
        for (int row = 0; row < 4; ++row) {
#pragma unroll
            for (int m = 0; m < 8; ++m) {
                float v = sv[row][m]; int n = si[row][m];
#pragma unroll
                for (int p = 0; p < T_CAND; ++p) {
                    if (v > v16[p]) {
                        float tv = v16[p]; v16[p] = v; v = tv;
                        int ti = i16[p]; i16[p] = n; n = ti;
                    }
                }
            }
        }
#pragma unroll
        for (int m = 0; m < T_CAND; ++m) ci[m] = i16[m];
    }
    __syncthreads();

    // exact f32 rescore; wave w -> candidates w*4..w*4+3
    {
        const int w = t >> 6, lane = t & 63;
        for (int cc = 0; cc < 4; ++cc) {
            int c = w * 4 + cc;
            int row = ci[c];
            const float* kp = ke + (size_t)row * DD + lane * 12;
            const float* qp = q + qi * DD + lane * 12;
            float d = 0.f, ks = 0.f;
#pragma unroll
            for (int i = 0; i < 12; ++i) {
                float kv = kp[i];
                d = fmaf(qp[i], kv, d);
                ks = fmaf(kv, kv, ks);
            }
#pragma unroll
            for (int off = 32; off > 0; off >>= 1) {
                d += __shfl_xor(d, off, 64);
                ks += __shfl_xor(ks, off, 64);
            }
            if (lane == 0)
                cs_[c] = d / fmaxf(qn[qi] * sqrtf(ks), 1e-8f);
        }
    }
    __syncthreads();

    // final top-5 of 16 (tie -> lower index)
    if (t == 0) {
        float v5[K_TOP]; int i5[K_TOP];
#pragma unroll
        for (int m = 0; m < K_TOP; ++m) { v5[m] = -FLT_MAX; i5[m] = INT_MAX; }
        for (int c = 0; c < T_CAND; ++c) {
            float v = cs_[c]; int n = ci[c];
#pragma unroll
            for (int m = 0; m < K_TOP; ++m) {
                bool take = (v > v5[m]) || (v == v5[m] && n < i5[m]);
                if (take) {
                    float tv = v5[m]; v5[m] = v; v = tv;
                    int ti = i5[m]; i5[m] = n; n = ti;
                }
            }
        }
#pragma unroll
        for (int m = 0; m < K_TOP; ++m) fi[m] = i5[m];
    }
    __syncthreads();

    // gather knowledge_full rows (ints < 30000 exact in f32)
    for (int pos = t; pos < K_TOP * LK; pos += 256) {
        int m = pos >> 5, lgi = pos & 31;
        out[(qi * K_TOP + m) * LK + lgi] = (float)kf[(size_t)fi[m] * LK + lgi];
    }
    // gather embed rows
    const int EO = BQ * K_TOP * LK;  // 10240
    for (int m = 0; m < K_TOP; ++m) {
        const float4* srcp = (const float4*)(ke + (size_t)fi[m] * DD);
        float4* dstp = (float4*)(out + EO + (size_t)(qi * K_TOP + m) * DD);
        for (int pos = t; pos < DD / 4; pos += 256) dstp[pos] = srcp[pos];
    }
}

extern "C" void kernel_launch(void* const* d_in, const int* in_sizes, int n_in,
                              void* d_out, int out_size, void* d_ws, size_t ws_size,
                              hipStream_t stream) {
    const float* query = (const float*)d_in[0];
    const float* ke    = (const float*)d_in[1];
    const int*   kf    = (const int*)d_in[2];
    float* out = (float*)d_out;

    // ws layout: pv [64][512][8] float2 (2.1 MB) | qf [24*4*64*8] ushort | qn[64]
    float2* pv = (float2*)d_ws;
    ushort* qf = (ushort*)((char*)d_ws + (size_t)BQ * NBLKS * 8 * sizeof(float2));
    float*  qn = (float*)((char*)qf + (size_t)24 * 4 * 64 * 8 * sizeof(ushort));

    prep_kernel<<<BQ, 256, 0, stream>>>(query, qf, qn);
    sims_kernel<<<NBLKS, 256, 0, stream>>>(qf, ke, pv);
    merge_rescore_kernel<<<BQ, 256, 0, stream>>>(pv, query, ke, kf, qn, out);
}